// Round 9
// baseline (137.102 us; speedup 1.0000x reference)
//
#include <hip/hip_runtime.h>

// Problem constants (fixed by the reference setup)
#define Bd 4
#define Cd 64
#define HWp 262144           // 512*512 = 2^18 pixels per image
#define NSd 2048
#define NLd 1000

// Sort geometry: 256 blocks total, 64 per image, 4096 pixels per block.
#define NBLK   256
#define JB     64            // sort blocks per image
#define PXB    4096          // pixels per sort block
#define PXB4   (PXB / 4)     // int4 per sort block

typedef float  __attribute__((ext_vector_type(4))) floatx4;

// ===========================================================================
// FAST PATH (block-local counting sort; no image-wide scan at all):
//   rank_kernel : per-4096px block: hist -> local 1000-scan -> local ranks
//                 rank[p] = g_local*4096 + localPos  (stays inside the block's
//                 own 4096-row xt window -> streaming-local transpose writes)
//   transpose   : x[b][C][HW] f32 -> xt[b][rank[p]][C] bf16-pair rows
//   sum         : per label: walk its 64 runs (blockCnt/localStart per g),
//                 2 rows per wave-instr, shfl-reduce, fused divide
//   gather      : edge endpoint means + edge weights
// ws layout (int-element offsets):
//   blockCnt   [B*NL*JB]   int    per-(image,label,block) count, g-minor
//   localSt    [B*NL*JB]   int    per-(image,label,block) local start, g-minor
//   rank       [B*HW]      int    block-local sorted position of each pixel
//   means      [B*NL*C]    float  channel-minor
//   xt         [B*HW*C/2]  u32    bf16 pairs
// ===========================================================================
#define OFF_BCNT   0
#define OFF_LST    (Bd * NLd * JB)
#define OFF_RANK   (2 * Bd * NLd * JB)
#define OFF_MEANS  (OFF_RANK + Bd * HWp)
#define OFF_XT     (OFF_MEANS + Bd * NLd * Cd)
#define WS_ELEMS   (OFF_XT + Bd * HWp * (Cd / 2))

__device__ __forceinline__ unsigned short f2bf(float f) {
    unsigned u = __float_as_uint(f);
    u += 0x7FFFu + ((u >> 16) & 1u);          // round-to-nearest-even
    return (unsigned short)(u >> 16);
}
__device__ __forceinline__ float bflo(unsigned u) { return __uint_as_float(u << 16); }
__device__ __forceinline__ float bfhi(unsigned u) { return __uint_as_float(u & 0xFFFF0000u); }
__device__ __forceinline__ int clampl(int l) {
    return (l < 0) ? 0 : (l >= NLd ? NLd - 1 : l);
}

// ---------------------------------------------------------------------------
// 1) fused block-local sort: hist + exclusive 1000-scan + cursor ranks.
//    grid = NBLK, block = 1024. Writes blockCnt/localSt columns + rank.
// ---------------------------------------------------------------------------
__global__ __launch_bounds__(1024)
void rank_kernel(const int* __restrict__ lab,
                 int* __restrict__ blockCnt, int* __restrict__ localSt,
                 int* __restrict__ rank) {
    __shared__ int h[1024];    // hist -> inclusive scan
    __shared__ int st[1024];   // exclusive prefix -> cursor
    const int tid = threadIdx.x;
    const int g   = blockIdx.x;          // 0..NBLK-1
    const int b   = g >> 6;              // JB = 64
    const int gl  = g & 63;

    h[tid] = 0;
    __syncthreads();

    // histogram: 1024 threads x 1 int4 = 4096 pixels
    const int4 lv = ((const int4*)(lab + ((size_t)b << 18) + gl * PXB))[tid];
    const int l0 = clampl(lv.x), l1 = clampl(lv.y),
              l2 = clampl(lv.z), l3 = clampl(lv.w);
    atomicAdd(&h[l0], 1);
    atomicAdd(&h[l1], 1);
    atomicAdd(&h[l2], 1);
    atomicAdd(&h[l3], 1);
    __syncthreads();

    const int v = h[tid];                // this label's count
    if (tid < NLd)
        blockCnt[((size_t)(b * NLd + tid) << 6) + gl] = v;

    // inclusive Hillis-Steele scan of h
    for (int off = 1; off < 1024; off <<= 1) {
        int t = (tid >= off) ? h[tid - off] : 0;
        __syncthreads();
        h[tid] += t;
        __syncthreads();
    }
    st[tid] = h[tid] - v;                // exclusive prefix
    if (tid < NLd)
        localSt[((size_t)(b * NLd + tid) << 6) + gl] = st[tid];
    __syncthreads();

    // cursor phase: block-local sorted position
    int4 rv;
    rv.x = (gl << 12) + atomicAdd(&st[l0], 1);
    rv.y = (gl << 12) + atomicAdd(&st[l1], 1);
    rv.z = (gl << 12) + atomicAdd(&st[l2], 1);
    rv.w = (gl << 12) + atomicAdd(&st[l3], 1);
    rv.x = (rv.x < 0) ? 0 : (rv.x >= HWp ? HWp - 1 : rv.x);
    rv.y = (rv.y < 0) ? 0 : (rv.y >= HWp ? HWp - 1 : rv.y);
    rv.z = (rv.z < 0) ? 0 : (rv.z >= HWp ? HWp - 1 : rv.z);
    rv.w = (rv.w < 0) ? 0 : (rv.w >= HWp ? HWp - 1 : rv.w);
    ((int4*)(rank + ((size_t)b << 18) + gl * PXB))[tid] = rv;
}

// ---------------------------------------------------------------------------
// 2) transpose + scatter: x[b][C][HW] f32 -> xt[b][rank[p]][C] bf16 pairs.
//    grid = (HW/64, B), block = 256. x loads nontemporal (read-once).
//    All 64 pixels of a transpose block scatter into ONE 512KB xt window.
// ---------------------------------------------------------------------------
__global__ __launch_bounds__(256)
void transpose_kernel(const float* __restrict__ x, const int* __restrict__ rank,
                      unsigned* __restrict__ xt) {
    __shared__ float lds[64 * 65];
    __shared__ int rnk[64];
    const int tid = threadIdx.x;
    const int p0  = blockIdx.x * 64;
    const int b   = blockIdx.y;
    const float* __restrict__ xb = x + ((size_t)b * Cd << 18);

    if (tid < 64) {
        int r = rank[((size_t)b << 18) + p0 + tid];
        rnk[tid] = (r < 0) ? 0 : (r >= HWp ? HWp - 1 : r);
    }

    #pragma unroll
    for (int it = 0; it < 4; ++it) {
        const int c = it * 16 + (tid >> 4);
        const int j = tid & 15;
        floatx4 v = __builtin_nontemporal_load(
            (const floatx4*)(xb + ((size_t)c << 18) + p0 + 4 * j));
        lds[(4 * j + 0) * 65 + c] = v.x;
        lds[(4 * j + 1) * 65 + c] = v.y;
        lds[(4 * j + 2) * 65 + c] = v.z;
        lds[(4 * j + 3) * 65 + c] = v.w;
    }
    __syncthreads();

    unsigned* __restrict__ xb_t = xt + (((size_t)b << 18) << 5);   // b*HW*32
    #pragma unroll
    for (int it = 0; it < 8; ++it) {
        const int p  = it * 8 + (tid >> 5);
        const int cp = tid & 31;
        float lo = lds[p * 65 + 2 * cp];
        float hi = lds[p * 65 + 2 * cp + 1];
        unsigned packed = ((unsigned)f2bf(hi) << 16) | (unsigned)f2bf(lo);
        xb_t[((size_t)rnk[p] << 5) + cp] = packed;
    }
}

// ---------------------------------------------------------------------------
// 3) label sums: wave per (b,l); walk 64 block-runs. Lane = (ps 0..1, c 0..31);
//    2 rows (256B contiguous) per wave-load. grid = (250, B), block = 256.
// ---------------------------------------------------------------------------
__global__ __launch_bounds__(256)
void sum_kernel(const unsigned* __restrict__ xt,
                const int* __restrict__ blockCnt, const int* __restrict__ localSt,
                float* __restrict__ means) {
    const int tid  = threadIdx.x;
    const int b    = blockIdx.y;
    const int l    = blockIdx.x * 4 + (tid >> 6);
    const int lane = tid & 63;
    const int ps   = lane >> 5;     // pixel parity 0..1
    const int c    = lane & 31;     // channel pair 0..31

    // lane g holds run metadata for sort block g (coalesced 64-int rows)
    int cntg = blockCnt[((size_t)(b * NLd + l) << 6) + lane];
    int stg  = localSt [((size_t)(b * NLd + l) << 6) + lane];
    if (stg < 0) stg = 0; if (stg > PXB) stg = PXB;
    if (cntg < 0) cntg = 0;
    if (cntg > PXB - stg) cntg = PXB - stg;

    // total pixel count for this label (wave reduce)
    int n = cntg;
    #pragma unroll
    for (int off = 1; off < 64; off <<= 1) n += __shfl_xor(n, off, 64);

    const unsigned* __restrict__ xb = xt + (((size_t)b << 18) << 5);

    float a0 = 0.0f, a1 = 0.0f;
    for (int g = 0; g < JB; ++g) {
        const int ng = __shfl(cntg, g, 64);
        const int sg = __shfl(stg,  g, 64);
        const unsigned* __restrict__ rb = xb + (((size_t)((g << 12) + sg)) << 5) + c;
        for (int pix = ps; pix < ng; pix += 2) {
            unsigned u = rb[(size_t)pix << 5];
            a0 += bflo(u);
            a1 += bfhi(u);
        }
    }

    a0 += __shfl_xor(a0, 32, 64);
    a1 += __shfl_xor(a1, 32, 64);

    if (ps == 0) {
        const float inv = 1.0f / (float)(n > 0 ? n : 1);
        float2 o; o.x = a0 * inv; o.y = a1 * inv;
        *(float2*)(means + (((size_t)(b * NLd + l)) << 6) + 2 * c) = o;
    }
}

// ---------------------------------------------------------------------------
// 4) gather means at edge endpoints + copy edge weights.
// ---------------------------------------------------------------------------
__global__ __launch_bounds__(256)
void gather_kernel(const float* __restrict__ means,
                   const int* __restrict__ edges,
                   const float* __restrict__ ew,
                   float* __restrict__ out) {
    const int t  = blockIdx.x * 256 + threadIdx.x;   // 0 .. B*NS*C-1
    const int bs = t >> 6;                           // b*NS + s
    const int c  = t & 63;
    const int b  = bs >> 11;                         // NS = 2048

    const int la = clampl(edges[bs * 2 + 0]);
    const int lb = clampl(edges[bs * 2 + 1]);

    out[t] = means[((size_t)(b * NLd + la) << 6) + c];
    out[(size_t)Bd * NSd * Cd + t] = means[((size_t)(b * NLd + lb) << 6) + c];
    if (t < Bd * NSd)
        out[2 * (size_t)Bd * NSd * Cd + t] = ew[t];
}

// ===========================================================================
// FALLBACK PATH (R1 design, known-good 371 us; needs ~1 MB ws)
// ===========================================================================
#define WS_FB_ELEMS (Bd * Cd * NLd + Bd * NLd)

__global__ __launch_bounds__(256)
void fb_sums_kernel(const float* __restrict__ x, const int* __restrict__ lab,
                    float* __restrict__ sums) {
    __shared__ float lsum[NLd];
    const int tid   = threadIdx.x;
    const int chunk = blockIdx.x;
    const int c     = blockIdx.y;
    const int b     = blockIdx.z;

    for (int l = tid; l < NLd; l += 256) lsum[l] = 0.0f;
    __syncthreads();

    const float4* __restrict__ xp =
        (const float4*)x + (size_t)(b * Cd + c) * (HWp / 4);
    const int4* __restrict__ lp = (const int4*)lab + (size_t)b * (HWp / 4);

    const int nvec = HWp / 16;
    const int v0 = chunk * nvec, v1 = v0 + nvec;
    for (int v = v0 + tid; v < v1; v += 256) {
        float4 xv = xp[v];
        int4   lv = lp[v];
        atomicAdd(&lsum[clampl(lv.x)], xv.x);
        atomicAdd(&lsum[clampl(lv.y)], xv.y);
        atomicAdd(&lsum[clampl(lv.z)], xv.z);
        atomicAdd(&lsum[clampl(lv.w)], xv.w);
    }
    __syncthreads();

    float* __restrict__ dst = sums + (size_t)(b * Cd + c) * NLd;
    for (int l = tid; l < NLd; l += 256)
        atomicAdd(&dst[l], lsum[l]);
}

__global__ __launch_bounds__(256)
void fb_counts_kernel(const int* __restrict__ lab, float* __restrict__ counts) {
    __shared__ unsigned lcnt[NLd];
    const int tid   = threadIdx.x;
    const int chunk = blockIdx.x;
    const int b     = blockIdx.y;

    for (int l = tid; l < NLd; l += 256) lcnt[l] = 0u;
    __syncthreads();

    const int4* __restrict__ lp = (const int4*)lab + (size_t)b * (HWp / 4);
    const int nvec = HWp / 16;
    const int v0 = chunk * nvec, v1 = v0 + nvec;
    for (int v = v0 + tid; v < v1; v += 256) {
        int4 lv = lp[v];
        atomicAdd(&lcnt[clampl(lv.x)], 1u);
        atomicAdd(&lcnt[clampl(lv.y)], 1u);
        atomicAdd(&lcnt[clampl(lv.z)], 1u);
        atomicAdd(&lcnt[clampl(lv.w)], 1u);
    }
    __syncthreads();

    float* __restrict__ dst = counts + (size_t)b * NLd;
    for (int l = tid; l < NLd; l += 256)
        atomicAdd(&dst[l], (float)lcnt[l]);
}

__global__ __launch_bounds__(256)
void fb_gather_kernel(const float* __restrict__ sums,
                      const float* __restrict__ counts,
                      const int* __restrict__ edges,
                      const float* __restrict__ ew,
                      float* __restrict__ out) {
    const int t  = blockIdx.x * 256 + threadIdx.x;
    const int bs = t >> 6;
    const int c  = t & 63;
    const int b  = bs >> 11;

    const int la = clampl(edges[bs * 2 + 0]);
    const int lb = clampl(edges[bs * 2 + 1]);

    const float ca = fmaxf(counts[b * NLd + la], 1.0f);
    const float cb = fmaxf(counts[b * NLd + lb], 1.0f);

    const size_t plane = (size_t)(b * Cd + c) * NLd;
    out[t] = sums[plane + la] / ca;
    out[(size_t)Bd * NSd * Cd + t] = sums[plane + lb] / cb;
    if (t < Bd * NSd)
        out[2 * (size_t)Bd * NSd * Cd + t] = ew[t];
}

extern "C" void kernel_launch(void* const* d_in, const int* in_sizes, int n_in,
                              void* d_out, int out_size, void* d_ws, size_t ws_size,
                              hipStream_t stream) {
    const float* x     = (const float*)d_in[0];   // [B,C,H,W] f32
    const int*   lab   = (const int*)d_in[1];     // [B,1,H,W] i32
    const int*   edges = (const int*)d_in[2];     // [B,NS,2] i32
    const float* ew    = (const float*)d_in[3];   // [B,NS] f32
    float*       out   = (float*)d_out;

    const int n_gather = Bd * NSd * Cd;   // 524288

    if (ws_size >= (size_t)WS_ELEMS * sizeof(int)) {
        int*      wsi       = (int*)d_ws;
        int*      blockCnt  = wsi + OFF_BCNT;
        int*      localSt   = wsi + OFF_LST;
        int*      rank      = wsi + OFF_RANK;
        float*    means     = (float*)(wsi + OFF_MEANS);
        unsigned* xt        = (unsigned*)(wsi + OFF_XT);

        rank_kernel<<<NBLK, 1024, 0, stream>>>(lab, blockCnt, localSt, rank);
        transpose_kernel<<<dim3(HWp / 64, Bd), 256, 0, stream>>>(x, rank, xt);
        sum_kernel<<<dim3(NLd / 4, Bd), 256, 0, stream>>>(xt, blockCnt, localSt, means);
        gather_kernel<<<n_gather / 256, 256, 0, stream>>>(means, edges, ew, out);
    } else {
        // ---- fallback: R1 atomic path ----
        float* sums   = (float*)d_ws;
        float* counts = sums + (size_t)Bd * Cd * NLd;

        hipMemsetAsync(d_ws, 0, (size_t)WS_FB_ELEMS * sizeof(float), stream);

        fb_sums_kernel<<<dim3(4, Cd, Bd), 256, 0, stream>>>(x, lab, sums);
        fb_counts_kernel<<<dim3(4, Bd), 256, 0, stream>>>(lab, counts);
        fb_gather_kernel<<<n_gather / 256, 256, 0, stream>>>(sums, counts, edges, ew, out);
    }
}

// Round 10
// 108.407 us; speedup vs baseline: 1.2647x; 1.2647x over previous
//
#include <hip/hip_runtime.h>

// Problem constants (fixed by the reference setup)
#define Bd 4
#define Cd 64
#define HWp 262144           // 512*512 = 2^18 pixels per image
#define NSd 2048
#define NLd 1000

// Hist geometry: 256 blocks total, 64 per image, 4096 pixels per block.
#define NBLK   256
#define PXB    4096          // pixels per hist block
#define PXB4   (PXB / 4)
// Sort-window geometry: 8 windows per image, 32768 pixels each (8 hist blocks).
#define NW     8             // windows per image
#define WPX    32768         // pixels per window

typedef float  __attribute__((ext_vector_type(4))) floatx4;

// ===========================================================================
// FAST PATH (window-local counting sort, 32768-px windows):
//   blockcnt : per-4096px hist
//   scan     : per-(image,window): totals over 8 hist blocks -> 1000-scan ->
//              winCnt/winStart (image-global) + per-hist blockBase
//   rank     : block cursor from blockBase -> image-global sorted position
//              (stays inside the window's 4MB xt region)
//   transpose: x[b][C][HW] f32 -> xt[b][rank[p]][C] bf16-pair rows
//   sum      : wave per (b,l): 8 contiguous runs (avg 33 rows), uint4 lanes
//   gather   : edge endpoint means + edge weights
// ws layout (int-element offsets):
//   blockCnt [NBLK*NL]   int
//   winCnt   [B*NW*NL]   int
//   winStart [B*NW*NL]   int   image-global row offsets
//   blockBase[NBLK*NL]   int
//   rank     [B*HW]      int
//   means    [B*NL*C]    float
//   xt       [B*HW*C/2]  u32   bf16 pairs
// ===========================================================================
#define OFF_BCNT   0
#define OFF_WCNT   (NBLK * NLd)
#define OFF_WST    (OFF_WCNT + Bd * NW * NLd)
#define OFF_BBASE  (OFF_WST + Bd * NW * NLd)
#define OFF_RANK   (OFF_BBASE + NBLK * NLd)
#define OFF_MEANS  (OFF_RANK + Bd * HWp)
#define OFF_XT     (OFF_MEANS + Bd * NLd * Cd)
#define WS_ELEMS   (OFF_XT + Bd * HWp * (Cd / 2))

__device__ __forceinline__ unsigned short f2bf(float f) {
    unsigned u = __float_as_uint(f);
    u += 0x7FFFu + ((u >> 16) & 1u);          // round-to-nearest-even
    return (unsigned short)(u >> 16);
}
__device__ __forceinline__ float bflo(unsigned u) { return __uint_as_float(u << 16); }
__device__ __forceinline__ float bfhi(unsigned u) { return __uint_as_float(u & 0xFFFF0000u); }
__device__ __forceinline__ int clampl(int l) {
    return (l < 0) ? 0 : (l >= NLd ? NLd - 1 : l);
}

// ---------------------------------------------------------------------------
// 1) per-block label histogram. grid = NBLK, block = 256.
// ---------------------------------------------------------------------------
__global__ __launch_bounds__(256)
void blockcnt_kernel(const int* __restrict__ lab, int* __restrict__ blockCnt) {
    __shared__ unsigned h[NLd];
    const int tid = threadIdx.x;
    const int g   = blockIdx.x;

    for (int l = tid; l < NLd; l += 256) h[l] = 0u;
    __syncthreads();

    const int4* __restrict__ lp = (const int4*)lab + (size_t)g * PXB4;
    for (int v = tid; v < PXB4; v += 256) {
        int4 lv = lp[v];
        atomicAdd(&h[clampl(lv.x)], 1u);
        atomicAdd(&h[clampl(lv.y)], 1u);
        atomicAdd(&h[clampl(lv.z)], 1u);
        atomicAdd(&h[clampl(lv.w)], 1u);
    }
    __syncthreads();

    int* __restrict__ dst = blockCnt + (size_t)g * NLd;
    for (int l = tid; l < NLd; l += 256) dst[l] = (int)h[l];
}

// ---------------------------------------------------------------------------
// 2) per-(image,window) totals + 1000-scan + per-hist-block bases.
//    grid = (NW, B), block = 1024. winStart/blockBase are image-global.
// ---------------------------------------------------------------------------
__global__ __launch_bounds__(1024)
void scan_kernel(const int* __restrict__ blockCnt, int* __restrict__ winCnt,
                 int* __restrict__ winStart, int* __restrict__ blockBase) {
    __shared__ int buf[1024];
    const int tid = threadIdx.x;
    const int w   = blockIdx.x;          // 0..NW-1
    const int b   = blockIdx.y;

    int tot = 0;
    if (tid < NLd) {
        #pragma unroll
        for (int j = 0; j < 8; ++j)
            tot += blockCnt[(size_t)(b * 64 + w * 8 + j) * NLd + tid];
    }
    buf[tid] = (tid < NLd) ? tot : 0;
    __syncthreads();
    for (int off = 1; off < 1024; off <<= 1) {
        int t = (tid >= off) ? buf[tid - off] : 0;
        __syncthreads();
        buf[tid] += t;
        __syncthreads();
    }
    if (tid < NLd) {
        const int st = (w << 15) + buf[tid] - tot;   // image-global row start
        winCnt  [(size_t)(b * NW + w) * NLd + tid] = tot;
        winStart[(size_t)(b * NW + w) * NLd + tid] = st;
        int run = st;
        #pragma unroll
        for (int j = 0; j < 8; ++j) {
            const size_t idx = (size_t)(b * 64 + w * 8 + j) * NLd + tid;
            blockBase[idx] = run;
            run += blockCnt[idx];
        }
    }
}

// ---------------------------------------------------------------------------
// 3) rank: sorted position per pixel (image-global, window-confined).
// ---------------------------------------------------------------------------
__global__ __launch_bounds__(256)
void rank_kernel(const int* __restrict__ lab, const int* __restrict__ blockBase,
                 int* __restrict__ rank) {
    __shared__ unsigned h[NLd];
    __shared__ int base[NLd];
    const int tid = threadIdx.x;
    const int g   = blockIdx.x;
    const int b   = g >> 6;              // 64 hist blocks per image
    const int p0  = (g & 63) * PXB;

    for (int l = tid; l < NLd; l += 256) {
        h[l] = 0u;
        base[l] = blockBase[(size_t)g * NLd + l];
    }
    __syncthreads();

    const int4* __restrict__ lp = (const int4*)(lab + ((size_t)b << 18) + p0);
    int4* __restrict__ rp = (int4*)(rank + ((size_t)b << 18) + p0);

    for (int v = tid; v < PXB4; v += 256) {
        int4 lv = lp[v];
        int l0 = clampl(lv.x), l1 = clampl(lv.y), l2 = clampl(lv.z), l3 = clampl(lv.w);
        int4 rv;
        rv.x = base[l0] + (int)atomicAdd(&h[l0], 1u);
        rv.y = base[l1] + (int)atomicAdd(&h[l1], 1u);
        rv.z = base[l2] + (int)atomicAdd(&h[l2], 1u);
        rv.w = base[l3] + (int)atomicAdd(&h[l3], 1u);
        rv.x = (rv.x < 0) ? 0 : (rv.x >= HWp ? HWp - 1 : rv.x);
        rv.y = (rv.y < 0) ? 0 : (rv.y >= HWp ? HWp - 1 : rv.y);
        rv.z = (rv.z < 0) ? 0 : (rv.z >= HWp ? HWp - 1 : rv.z);
        rv.w = (rv.w < 0) ? 0 : (rv.w >= HWp ? HWp - 1 : rv.w);
        rp[v] = rv;
    }
}

// ---------------------------------------------------------------------------
// 4) transpose + scatter: x[b][C][HW] f32 -> xt[b][rank[p]][C] bf16 pairs.
//    grid = (HW/64, B), block = 256. x loads nontemporal (read-once).
//    Scatter confined to the pixel's 4MB window.
// ---------------------------------------------------------------------------
__global__ __launch_bounds__(256)
void transpose_kernel(const float* __restrict__ x, const int* __restrict__ rank,
                      unsigned* __restrict__ xt) {
    __shared__ float lds[64 * 65];
    __shared__ int rnk[64];
    const int tid = threadIdx.x;
    const int p0  = blockIdx.x * 64;
    const int b   = blockIdx.y;
    const float* __restrict__ xb = x + ((size_t)b * Cd << 18);

    if (tid < 64) {
        int r = rank[((size_t)b << 18) + p0 + tid];
        rnk[tid] = (r < 0) ? 0 : (r >= HWp ? HWp - 1 : r);
    }

    #pragma unroll
    for (int it = 0; it < 4; ++it) {
        const int c = it * 16 + (tid >> 4);
        const int j = tid & 15;
        floatx4 v = __builtin_nontemporal_load(
            (const floatx4*)(xb + ((size_t)c << 18) + p0 + 4 * j));
        lds[(4 * j + 0) * 65 + c] = v.x;
        lds[(4 * j + 1) * 65 + c] = v.y;
        lds[(4 * j + 2) * 65 + c] = v.z;
        lds[(4 * j + 3) * 65 + c] = v.w;
    }
    __syncthreads();

    unsigned* __restrict__ xb_t = xt + (((size_t)b << 18) << 5);   // b*HW*32
    #pragma unroll
    for (int it = 0; it < 8; ++it) {
        const int p  = it * 8 + (tid >> 5);
        const int cp = tid & 31;
        float lo = lds[p * 65 + 2 * cp];
        float hi = lds[p * 65 + 2 * cp + 1];
        unsigned packed = ((unsigned)f2bf(hi) << 16) | (unsigned)f2bf(lo);
        xb_t[((size_t)rnk[p] << 5) + cp] = packed;
    }
}

// ---------------------------------------------------------------------------
// 5) label sums: wave per (b,l); 8 contiguous window-runs (avg 33 rows).
//    Lane = (ps 0..7 pixel slot, q 0..7 uint4 slot): 8 rows x 128B per
//    wave-load, fully coalesced. grid = (250, B), block = 256.
// ---------------------------------------------------------------------------
__global__ __launch_bounds__(256)
void sum_kernel(const unsigned* __restrict__ xt,
                const int* __restrict__ winCnt, const int* __restrict__ winStart,
                float* __restrict__ means) {
    const int tid  = threadIdx.x;
    const int b    = blockIdx.y;
    const int l    = blockIdx.x * 4 + (tid >> 6);
    const int lane = tid & 63;
    const int ps   = lane >> 3;     // pixel slot 0..7
    const int q    = lane & 7;      // uint4 slot within row (8 channels)

    // lanes 0..NW-1 hold per-window run metadata
    int cw = 0, sw = 0;
    if (lane < NW) {
        cw = winCnt  [(size_t)(b * NW + lane) * NLd + l];
        sw = winStart[(size_t)(b * NW + lane) * NLd + l];
        if (sw < 0) sw = 0; if (sw > HWp) sw = HWp;
        if (cw < 0) cw = 0;
        if (cw > HWp - sw) cw = HWp - sw;
    }

    int n = cw;
    #pragma unroll
    for (int off = 1; off < 64; off <<= 1) n += __shfl_xor(n, off, 64);

    const uint4* __restrict__ xb = (const uint4*)(xt + (((size_t)b << 18) << 5));

    float a0 = 0, a1 = 0, a2 = 0, a3 = 0, a4 = 0, a5 = 0, a6 = 0, a7 = 0;
    for (int w = 0; w < NW; ++w) {
        const int ng = __shfl(cw, w, 64);
        const int sg = __shfl(sw, w, 64);
        const uint4* __restrict__ rb = xb + ((size_t)sg << 3) + q;
        for (int pix = ps; pix < ng; pix += 8) {
            uint4 u = rb[(size_t)pix << 3];
            a0 += bflo(u.x); a1 += bfhi(u.x);
            a2 += bflo(u.y); a3 += bfhi(u.y);
            a4 += bflo(u.z); a5 += bfhi(u.z);
            a6 += bflo(u.w); a7 += bfhi(u.w);
        }
    }

    #pragma unroll
    for (int off = 8; off < 64; off <<= 1) {
        a0 += __shfl_xor(a0, off, 64);
        a1 += __shfl_xor(a1, off, 64);
        a2 += __shfl_xor(a2, off, 64);
        a3 += __shfl_xor(a3, off, 64);
        a4 += __shfl_xor(a4, off, 64);
        a5 += __shfl_xor(a5, off, 64);
        a6 += __shfl_xor(a6, off, 64);
        a7 += __shfl_xor(a7, off, 64);
    }

    if (ps == 0) {
        const float inv = 1.0f / (float)(n > 0 ? n : 1);
        float* dst = means + (((size_t)(b * NLd + l)) << 6) + q * 8;
        float4 o0; o0.x = a0 * inv; o0.y = a1 * inv; o0.z = a2 * inv; o0.w = a3 * inv;
        float4 o1; o1.x = a4 * inv; o1.y = a5 * inv; o1.z = a6 * inv; o1.w = a7 * inv;
        *(float4*)dst = o0;
        *(float4*)(dst + 4) = o1;
    }
}

// ---------------------------------------------------------------------------
// 6) gather means at edge endpoints + copy edge weights.
// ---------------------------------------------------------------------------
__global__ __launch_bounds__(256)
void gather_kernel(const float* __restrict__ means,
                   const int* __restrict__ edges,
                   const float* __restrict__ ew,
                   float* __restrict__ out) {
    const int t  = blockIdx.x * 256 + threadIdx.x;   // 0 .. B*NS*C-1
    const int bs = t >> 6;                           // b*NS + s
    const int c  = t & 63;
    const int b  = bs >> 11;                         // NS = 2048

    const int la = clampl(edges[bs * 2 + 0]);
    const int lb = clampl(edges[bs * 2 + 1]);

    out[t] = means[((size_t)(b * NLd + la) << 6) + c];
    out[(size_t)Bd * NSd * Cd + t] = means[((size_t)(b * NLd + lb) << 6) + c];
    if (t < Bd * NSd)
        out[2 * (size_t)Bd * NSd * Cd + t] = ew[t];
}

// ===========================================================================
// FALLBACK PATH (R1 design, known-good 371 us; needs ~1 MB ws)
// ===========================================================================
#define WS_FB_ELEMS (Bd * Cd * NLd + Bd * NLd)

__global__ __launch_bounds__(256)
void fb_sums_kernel(const float* __restrict__ x, const int* __restrict__ lab,
                    float* __restrict__ sums) {
    __shared__ float lsum[NLd];
    const int tid   = threadIdx.x;
    const int chunk = blockIdx.x;
    const int c     = blockIdx.y;
    const int b     = blockIdx.z;

    for (int l = tid; l < NLd; l += 256) lsum[l] = 0.0f;
    __syncthreads();

    const float4* __restrict__ xp =
        (const float4*)x + (size_t)(b * Cd + c) * (HWp / 4);
    const int4* __restrict__ lp = (const int4*)lab + (size_t)b * (HWp / 4);

    const int nvec = HWp / 16;
    const int v0 = chunk * nvec, v1 = v0 + nvec;
    for (int v = v0 + tid; v < v1; v += 256) {
        float4 xv = xp[v];
        int4   lv = lp[v];
        atomicAdd(&lsum[clampl(lv.x)], xv.x);
        atomicAdd(&lsum[clampl(lv.y)], xv.y);
        atomicAdd(&lsum[clampl(lv.z)], xv.z);
        atomicAdd(&lsum[clampl(lv.w)], xv.w);
    }
    __syncthreads();

    float* __restrict__ dst = sums + (size_t)(b * Cd + c) * NLd;
    for (int l = tid; l < NLd; l += 256)
        atomicAdd(&dst[l], lsum[l]);
}

__global__ __launch_bounds__(256)
void fb_counts_kernel(const int* __restrict__ lab, float* __restrict__ counts) {
    __shared__ unsigned lcnt[NLd];
    const int tid   = threadIdx.x;
    const int chunk = blockIdx.x;
    const int b     = blockIdx.y;

    for (int l = tid; l < NLd; l += 256) lcnt[l] = 0u;
    __syncthreads();

    const int4* __restrict__ lp = (const int4*)lab + (size_t)b * (HWp / 4);
    const int nvec = HWp / 16;
    const int v0 = chunk * nvec, v1 = v0 + nvec;
    for (int v = v0 + tid; v < v1; v += 256) {
        int4 lv = lp[v];
        atomicAdd(&lcnt[clampl(lv.x)], 1u);
        atomicAdd(&lcnt[clampl(lv.y)], 1u);
        atomicAdd(&lcnt[clampl(lv.z)], 1u);
        atomicAdd(&lcnt[clampl(lv.w)], 1u);
    }
    __syncthreads();

    float* __restrict__ dst = counts + (size_t)b * NLd;
    for (int l = tid; l < NLd; l += 256)
        atomicAdd(&dst[l], (float)lcnt[l]);
}

__global__ __launch_bounds__(256)
void fb_gather_kernel(const float* __restrict__ sums,
                      const float* __restrict__ counts,
                      const int* __restrict__ edges,
                      const float* __restrict__ ew,
                      float* __restrict__ out) {
    const int t  = blockIdx.x * 256 + threadIdx.x;
    const int bs = t >> 6;
    const int c  = t & 63;
    const int b  = bs >> 11;

    const int la = clampl(edges[bs * 2 + 0]);
    const int lb = clampl(edges[bs * 2 + 1]);

    const float ca = fmaxf(counts[b * NLd + la], 1.0f);
    const float cb = fmaxf(counts[b * NLd + lb], 1.0f);

    const size_t plane = (size_t)(b * Cd + c) * NLd;
    out[t] = sums[plane + la] / ca;
    out[(size_t)Bd * NSd * Cd + t] = sums[plane + lb] / cb;
    if (t < Bd * NSd)
        out[2 * (size_t)Bd * NSd * Cd + t] = ew[t];
}

extern "C" void kernel_launch(void* const* d_in, const int* in_sizes, int n_in,
                              void* d_out, int out_size, void* d_ws, size_t ws_size,
                              hipStream_t stream) {
    const float* x     = (const float*)d_in[0];   // [B,C,H,W] f32
    const int*   lab   = (const int*)d_in[1];     // [B,1,H,W] i32
    const int*   edges = (const int*)d_in[2];     // [B,NS,2] i32
    const float* ew    = (const float*)d_in[3];   // [B,NS] f32
    float*       out   = (float*)d_out;

    const int n_gather = Bd * NSd * Cd;   // 524288

    if (ws_size >= (size_t)WS_ELEMS * sizeof(int)) {
        int*      wsi       = (int*)d_ws;
        int*      blockCnt  = wsi + OFF_BCNT;
        int*      winCnt    = wsi + OFF_WCNT;
        int*      winStart  = wsi + OFF_WST;
        int*      blockBase = wsi + OFF_BBASE;
        int*      rank      = wsi + OFF_RANK;
        float*    means     = (float*)(wsi + OFF_MEANS);
        unsigned* xt        = (unsigned*)(wsi + OFF_XT);

        blockcnt_kernel<<<NBLK, 256, 0, stream>>>(lab, blockCnt);
        scan_kernel<<<dim3(NW, Bd), 1024, 0, stream>>>(blockCnt, winCnt, winStart, blockBase);
        rank_kernel<<<NBLK, 256, 0, stream>>>(lab, blockBase, rank);
        transpose_kernel<<<dim3(HWp / 64, Bd), 256, 0, stream>>>(x, rank, xt);
        sum_kernel<<<dim3(NLd / 4, Bd), 256, 0, stream>>>(xt, winCnt, winStart, means);
        gather_kernel<<<n_gather / 256, 256, 0, stream>>>(means, edges, ew, out);
    } else {
        // ---- fallback: R1 atomic path ----
        float* sums   = (float*)d_ws;
        float* counts = sums + (size_t)Bd * Cd * NLd;

        hipMemsetAsync(d_ws, 0, (size_t)WS_FB_ELEMS * sizeof(float), stream);

        fb_sums_kernel<<<dim3(4, Cd, Bd), 256, 0, stream>>>(x, lab, sums);
        fb_counts_kernel<<<dim3(4, Bd), 256, 0, stream>>>(lab, counts);
        fb_gather_kernel<<<n_gather / 256, 256, 0, stream>>>(sums, counts, edges, ew, out);
    }
}

// Round 11
// 97.562 us; speedup vs baseline: 1.4053x; 1.1112x over previous
//
#include <hip/hip_runtime.h>

// Problem constants (fixed by the reference setup)
#define Bd 4
#define Cd 64
#define HWp 262144           // 512*512 = 2^18 pixels per image
#define NSd 2048
#define NLd 1000

#define WIN    64            // windows per image
#define PXW    4096          // pixels per window
#define NBLK   (Bd * WIN)    // 256 fused blocks
#define NSL    8             // channel slices
#define CSL    8             // channels per slice
#define PROW   8000          // floats per partial row (1000 labels * 8 ch)

typedef float __attribute__((ext_vector_type(4))) floatx4;

// ===========================================================================
// FAST PATH (fully fused): per-window {hist -> scan -> ranks -> 8x slice
// {pack bf16 -> LDS scatter -> per-label lane sums}} -> partial sums;
// combine reduces 64 windows -> means; gather emits outputs.
// NO intermediate xt array: x is read once, partials are 64 MB vs xt's 271.
// ws layout (element offsets, 4B units):
//   partial  [NBLK*NSL*PROW] float   per-(window,slice) label sums
//   blockCnt [NBLK*NL]       int
//   means    [B*NL*C]        float
// ===========================================================================
#define OFF_PART  0
#define OFF_BCNT  (NBLK * NSL * PROW)
#define OFF_MEANS (OFF_BCNT + NBLK * NLd)
#define WS_ELEMS  (OFF_MEANS + Bd * NLd * Cd)

__device__ __forceinline__ unsigned short f2bf(float f) {
    unsigned u = __float_as_uint(f);
    u += 0x7FFFu + ((u >> 16) & 1u);          // round-to-nearest-even
    return (unsigned short)(u >> 16);
}
__device__ __forceinline__ unsigned pack2(float lo, float hi) {
    return ((unsigned)f2bf(hi) << 16) | (unsigned)f2bf(lo);
}
__device__ __forceinline__ float bflo(unsigned u) { return __uint_as_float(u << 16); }
__device__ __forceinline__ float bfhi(unsigned u) { return __uint_as_float(u & 0xFFFF0000u); }
__device__ __forceinline__ int clampl(int l) {
    return (l < 0) ? 0 : (l >= NLd ? NLd - 1 : l);
}

// ---------------------------------------------------------------------------
// 1) fused kernel. grid = NBLK, block = 1024 (thread owns 4 px).
// ---------------------------------------------------------------------------
__global__ __launch_bounds__(1024)
void fused_kernel(const float* __restrict__ x, const int* __restrict__ lab,
                  int* __restrict__ blockCnt, float* __restrict__ partial) {
    __shared__ int h[1024];          // per-label counts (kept)
    __shared__ int sc[1024];         // scan buffer -> starts
    __shared__ int cur[1024];        // cursors (consumed)
    __shared__ uint4 ordered[PXW];   // 64 KB: rank-ordered bf16 pixel rows

    const int tid = threadIdx.x;
    const int g   = blockIdx.x;
    const int b   = g >> 6;
    const int win = g & 63;
    const int p0  = win * PXW;

    h[tid] = 0;
    __syncthreads();

    // labels of my 4 pixels (px = 4*tid .. 4*tid+3 within window)
    const int4 lv = ((const int4*)(lab + ((size_t)b << 18) + p0))[tid];
    const int l0 = clampl(lv.x), l1 = clampl(lv.y),
              l2 = clampl(lv.z), l3 = clampl(lv.w);
    atomicAdd(&h[l0], 1);
    atomicAdd(&h[l1], 1);
    atomicAdd(&h[l2], 1);
    atomicAdd(&h[l3], 1);
    __syncthreads();

    const int myCnt = h[tid];
    sc[tid] = myCnt;
    __syncthreads();
    for (int off = 1; off < 1024; off <<= 1) {
        int t = (tid >= off) ? sc[tid - off] : 0;
        __syncthreads();
        sc[tid] += t;
        __syncthreads();
    }
    const int myst = sc[tid] - myCnt;      // exclusive prefix (my label's start)
    cur[tid] = myst;
    if (tid < NLd) blockCnt[(size_t)g * NLd + tid] = myCnt;
    __syncthreads();

    // block-local ranks of my 4 pixels (kept in registers)
    const int r0 = atomicAdd(&cur[l0], 1) & (PXW - 1);
    const int r1 = atomicAdd(&cur[l1], 1) & (PXW - 1);
    const int r2 = atomicAdd(&cur[l2], 1) & (PXW - 1);
    const int r3 = atomicAdd(&cur[l3], 1) & (PXW - 1);

    const float* __restrict__ xb = x + (((size_t)b * Cd) << 18) + p0 + 4 * tid;
    float* __restrict__ pout = partial + (size_t)g * NSL * PROW;

    // prologue: load + pack slice 0
    floatx4 v[CSL];
    #pragma unroll
    for (int c = 0; c < CSL; ++c)
        v[c] = __builtin_nontemporal_load((const floatx4*)(xb + ((size_t)c << 18)));
    uint4 pk[4];
    #pragma unroll
    for (int j = 0; j < 4; ++j) {
        pk[j].x = pack2(v[0][j], v[1][j]);
        pk[j].y = pack2(v[2][j], v[3][j]);
        pk[j].z = pack2(v[4][j], v[5][j]);
        pk[j].w = pack2(v[6][j], v[7][j]);
    }

    for (int s = 0; s < NSL; ++s) {
        __syncthreads();                 // previous slice's sums complete
        ordered[r0] = pk[0];
        ordered[r1] = pk[1];
        ordered[r2] = pk[2];
        ordered[r3] = pk[3];
        // issue next slice's global loads NOW: latency hides under sum phase
        if (s + 1 < NSL) {
            #pragma unroll
            for (int c = 0; c < CSL; ++c)
                v[c] = __builtin_nontemporal_load(
                    (const floatx4*)(xb + (((size_t)((s + 1) * CSL + c)) << 18)));
        }
        __syncthreads();                 // scatter visible

        if (tid < NLd) {
            float a0 = 0, a1 = 0, a2 = 0, a3 = 0, a4 = 0, a5 = 0, a6 = 0, a7 = 0;
            for (int i = 0; i < myCnt; ++i) {
                uint4 u = ordered[(myst + i) & (PXW - 1)];
                a0 += bflo(u.x); a1 += bfhi(u.x);
                a2 += bflo(u.y); a3 += bfhi(u.y);
                a4 += bflo(u.z); a5 += bfhi(u.z);
                a6 += bflo(u.w); a7 += bfhi(u.w);
            }
            float* dst = pout + (size_t)s * PROW + tid * 8;
            float4 o0; o0.x = a0; o0.y = a1; o0.z = a2; o0.w = a3;
            float4 o1; o1.x = a4; o1.y = a5; o1.z = a6; o1.w = a7;
            *(float4*)dst = o0;
            *(float4*)(dst + 4) = o1;
        }
        if (s + 1 < NSL) {
            #pragma unroll
            for (int j = 0; j < 4; ++j) {   // pack after sum (waits on loads)
                pk[j].x = pack2(v[0][j], v[1][j]);
                pk[j].y = pack2(v[2][j], v[3][j]);
                pk[j].z = pack2(v[4][j], v[5][j]);
                pk[j].w = pack2(v[6][j], v[7][j]);
            }
        }
    }
}

// ---------------------------------------------------------------------------
// 2) combine: reduce 64 windows -> means[b][l][c] (fused divide).
//    grid = (63, B) x 256 thr; thread t<128 owns (l_local = t>>3, j = t&7),
//    accumulates 8 slices in registers over 64 windows.
// ---------------------------------------------------------------------------
__global__ __launch_bounds__(256)
void combine_kernel(const float* __restrict__ partial,
                    const int* __restrict__ blockCnt,
                    float* __restrict__ means) {
    __shared__ float acc[16 * 65];
    __shared__ float ninv[16];
    const int tid = threadIdx.x;
    const int b   = blockIdx.y;
    const int l0  = blockIdx.x * 16;

    if (tid < 128) {
        float r0 = 0, r1 = 0, r2 = 0, r3 = 0, r4 = 0, r5 = 0, r6 = 0, r7 = 0;
        const float* __restrict__ pb =
            partial + (size_t)b * WIN * NSL * PROW + l0 * 8 + tid;
        for (int g = 0; g < WIN; ++g) {
            const float* __restrict__ pg = pb + (size_t)g * NSL * PROW;
            r0 += pg[0 * PROW]; r1 += pg[1 * PROW];
            r2 += pg[2 * PROW]; r3 += pg[3 * PROW];
            r4 += pg[4 * PROW]; r5 += pg[5 * PROW];
            r6 += pg[6 * PROW]; r7 += pg[7 * PROW];
        }
        const int ll = tid >> 3, j = tid & 7;
        float* a = acc + ll * 65 + j;
        a[0]  = r0; a[8]  = r1; a[16] = r2; a[24] = r3;
        a[32] = r4; a[40] = r5; a[48] = r6; a[56] = r7;
    }
    if (tid < 16) {
        int n = 0;
        for (int g = 0; g < WIN; ++g)
            n += blockCnt[(size_t)(b * WIN + g) * NLd + l0 + tid];
        ninv[tid] = 1.0f / (float)(n > 0 ? n : 1);
    }
    __syncthreads();

    const int f  = tid * 4;          // 256 thr x 4 = 1024 floats (16 l x 64 c)
    const int ll = f >> 6, c = f & 63;
    const int l  = l0 + ll;
    if (l < NLd) {
        const float sc = ninv[ll];
        const float* a = acc + ll * 65 + c;
        float4 o; o.x = a[0] * sc; o.y = a[1] * sc; o.z = a[2] * sc; o.w = a[3] * sc;
        *(float4*)(means + (((size_t)(b * NLd + l)) << 6) + c) = o;
    }
}

// ---------------------------------------------------------------------------
// 3) gather means at edge endpoints + copy edge weights.
// ---------------------------------------------------------------------------
__global__ __launch_bounds__(256)
void gather_kernel(const float* __restrict__ means,
                   const int* __restrict__ edges,
                   const float* __restrict__ ew,
                   float* __restrict__ out) {
    const int t  = blockIdx.x * 256 + threadIdx.x;   // 0 .. B*NS*C-1
    const int bs = t >> 6;                           // b*NS + s
    const int c  = t & 63;
    const int b  = bs >> 11;                         // NS = 2048

    const int la = clampl(edges[bs * 2 + 0]);
    const int lb = clampl(edges[bs * 2 + 1]);

    out[t] = means[((size_t)(b * NLd + la) << 6) + c];
    out[(size_t)Bd * NSd * Cd + t] = means[((size_t)(b * NLd + lb) << 6) + c];
    if (t < Bd * NSd)
        out[2 * (size_t)Bd * NSd * Cd + t] = ew[t];
}

// ===========================================================================
// FALLBACK PATH (R1 design, known-good 371 us; needs ~1 MB ws)
// ===========================================================================
#define WS_FB_ELEMS (Bd * Cd * NLd + Bd * NLd)

__global__ __launch_bounds__(256)
void fb_sums_kernel(const float* __restrict__ x, const int* __restrict__ lab,
                    float* __restrict__ sums) {
    __shared__ float lsum[NLd];
    const int tid   = threadIdx.x;
    const int chunk = blockIdx.x;
    const int c     = blockIdx.y;
    const int b     = blockIdx.z;

    for (int l = tid; l < NLd; l += 256) lsum[l] = 0.0f;
    __syncthreads();

    const float4* __restrict__ xp =
        (const float4*)x + (size_t)(b * Cd + c) * (HWp / 4);
    const int4* __restrict__ lp = (const int4*)lab + (size_t)b * (HWp / 4);

    const int nvec = HWp / 16;
    const int v0 = chunk * nvec, v1 = v0 + nvec;
    for (int v = v0 + tid; v < v1; v += 256) {
        float4 xv = xp[v];
        int4   lv = lp[v];
        atomicAdd(&lsum[clampl(lv.x)], xv.x);
        atomicAdd(&lsum[clampl(lv.y)], xv.y);
        atomicAdd(&lsum[clampl(lv.z)], xv.z);
        atomicAdd(&lsum[clampl(lv.w)], xv.w);
    }
    __syncthreads();

    float* __restrict__ dst = sums + (size_t)(b * Cd + c) * NLd;
    for (int l = tid; l < NLd; l += 256)
        atomicAdd(&dst[l], lsum[l]);
}

__global__ __launch_bounds__(256)
void fb_counts_kernel(const int* __restrict__ lab, float* __restrict__ counts) {
    __shared__ unsigned lcnt[NLd];
    const int tid   = threadIdx.x;
    const int chunk = blockIdx.x;
    const int b     = blockIdx.y;

    for (int l = tid; l < NLd; l += 256) lcnt[l] = 0u;
    __syncthreads();

    const int4* __restrict__ lp = (const int4*)lab + (size_t)b * (HWp / 4);
    const int nvec = HWp / 16;
    const int v0 = chunk * nvec, v1 = v0 + nvec;
    for (int v = v0 + tid; v < v1; v += 256) {
        int4 lv = lp[v];
        atomicAdd(&lcnt[clampl(lv.x)], 1u);
        atomicAdd(&lcnt[clampl(lv.y)], 1u);
        atomicAdd(&lcnt[clampl(lv.z)], 1u);
        atomicAdd(&lcnt[clampl(lv.w)], 1u);
    }
    __syncthreads();

    float* __restrict__ dst = counts + (size_t)b * NLd;
    for (int l = tid; l < NLd; l += 256)
        atomicAdd(&dst[l], (float)lcnt[l]);
}

__global__ __launch_bounds__(256)
void fb_gather_kernel(const float* __restrict__ sums,
                      const float* __restrict__ counts,
                      const int* __restrict__ edges,
                      const float* __restrict__ ew,
                      float* __restrict__ out) {
    const int t  = blockIdx.x * 256 + threadIdx.x;
    const int bs = t >> 6;
    const int c  = t & 63;
    const int b  = bs >> 11;

    const int la = clampl(edges[bs * 2 + 0]);
    const int lb = clampl(edges[bs * 2 + 1]);

    const float ca = fmaxf(counts[b * NLd + la], 1.0f);
    const float cb = fmaxf(counts[b * NLd + lb], 1.0f);

    const size_t plane = (size_t)(b * Cd + c) * NLd;
    out[t] = sums[plane + la] / ca;
    out[(size_t)Bd * NSd * Cd + t] = sums[plane + lb] / cb;
    if (t < Bd * NSd)
        out[2 * (size_t)Bd * NSd * Cd + t] = ew[t];
}

extern "C" void kernel_launch(void* const* d_in, const int* in_sizes, int n_in,
                              void* d_out, int out_size, void* d_ws, size_t ws_size,
                              hipStream_t stream) {
    const float* x     = (const float*)d_in[0];   // [B,C,H,W] f32
    const int*   lab   = (const int*)d_in[1];     // [B,1,H,W] i32
    const int*   edges = (const int*)d_in[2];     // [B,NS,2] i32
    const float* ew    = (const float*)d_in[3];   // [B,NS] f32
    float*       out   = (float*)d_out;

    const int n_gather = Bd * NSd * Cd;   // 524288

    if (ws_size >= (size_t)WS_ELEMS * sizeof(float)) {
        float* partial  = (float*)d_ws + OFF_PART;
        int*   blockCnt = (int*)d_ws + OFF_BCNT;
        float* means    = (float*)d_ws + OFF_MEANS;

        // no memset needed: partial/blockCnt/means are fully overwritten
        fused_kernel<<<NBLK, 1024, 0, stream>>>(x, lab, blockCnt, partial);
        combine_kernel<<<dim3(63, Bd), 256, 0, stream>>>(partial, blockCnt, means);
        gather_kernel<<<n_gather / 256, 256, 0, stream>>>(means, edges, ew, out);
    } else {
        // ---- fallback: R1 atomic path ----
        float* sums   = (float*)d_ws;
        float* counts = sums + (size_t)Bd * Cd * NLd;

        hipMemsetAsync(d_ws, 0, (size_t)WS_FB_ELEMS * sizeof(float), stream);

        fb_sums_kernel<<<dim3(4, Cd, Bd), 256, 0, stream>>>(x, lab, sums);
        fb_counts_kernel<<<dim3(4, Bd), 256, 0, stream>>>(lab, counts);
        fb_gather_kernel<<<n_gather / 256, 256, 0, stream>>>(sums, counts, edges, ew, out);
    }
}

// Round 12
// 86.524 us; speedup vs baseline: 1.5846x; 1.1276x over previous
//
#include <hip/hip_runtime.h>

// Problem constants (fixed by the reference setup)
#define Bd 4
#define Cd 64
#define HWp 262144           // 512*512 = 2^18 pixels per image
#define NSd 2048
#define NLd 1000

#define WIN    64            // windows per image
#define PXW    4096          // pixels per window
#define NBLK   (Bd * WIN)    // 256 fused blocks
#define NSL    16            // channel slices
#define CSL    4             // channels per slice
#define PROW   4000          // floats per partial row (1000 labels * 4 ch)

typedef float __attribute__((ext_vector_type(4))) floatx4;

// ===========================================================================
// FAST PATH (fully fused, 2 blocks/CU):
//   fused  : per-4096px window {hist -> in-place scan -> ranks -> 16x slice
//            {scatter bf16x4 rows into LDS -> per-label lane sums}} -> partial
//   combine: reduce 64 windows -> means (fused divide)
//   gather : edge endpoint means + edge weights
// ws layout (element offsets, 4B units):
//   partial  [NBLK*NSL*PROW] float
//   blockCnt [NBLK*NL]       int
//   means    [B*NL*C]        float
// ===========================================================================
#define OFF_PART  0
#define OFF_BCNT  (NBLK * NSL * PROW)
#define OFF_MEANS (OFF_BCNT + NBLK * NLd)
#define WS_ELEMS  (OFF_MEANS + Bd * NLd * Cd)

__device__ __forceinline__ unsigned short f2bf(float f) {
    unsigned u = __float_as_uint(f);
    u += 0x7FFFu + ((u >> 16) & 1u);          // round-to-nearest-even
    return (unsigned short)(u >> 16);
}
__device__ __forceinline__ unsigned pack2(float lo, float hi) {
    return ((unsigned)f2bf(hi) << 16) | (unsigned)f2bf(lo);
}
__device__ __forceinline__ float bflo(unsigned u) { return __uint_as_float(u << 16); }
__device__ __forceinline__ float bfhi(unsigned u) { return __uint_as_float(u & 0xFFFF0000u); }
__device__ __forceinline__ int clampl(int l) {
    return (l < 0) ? 0 : (l >= NLd ? NLd - 1 : l);
}

// ---------------------------------------------------------------------------
// 1) fused kernel. grid = NBLK, block = 1024 (thread owns 4 px).
//    LDS: 32KB ordered + 4KB h = 36KB; VGPR forced <=64 -> 2 blocks/CU.
// ---------------------------------------------------------------------------
__global__ __launch_bounds__(1024, 8)
void fused_kernel(const float* __restrict__ x, const int* __restrict__ lab,
                  int* __restrict__ blockCnt, float* __restrict__ partial) {
    __shared__ int h[1024];          // hist -> scan -> cursor (reused)
    __shared__ uint2 ordered[PXW];   // 32 KB: rank-ordered bf16x4 pixel rows

    const int tid = threadIdx.x;
    const int g   = blockIdx.x;
    const int b   = g >> 6;
    const int win = g & 63;
    const int p0  = win * PXW;

    h[tid] = 0;
    __syncthreads();

    // labels of my 4 pixels (px = 4*tid .. 4*tid+3 within window)
    const int4 lv = ((const int4*)(lab + ((size_t)b << 18) + p0))[tid];
    const int l0 = clampl(lv.x), l1 = clampl(lv.y),
              l2 = clampl(lv.z), l3 = clampl(lv.w);
    atomicAdd(&h[l0], 1);
    atomicAdd(&h[l1], 1);
    atomicAdd(&h[l2], 1);
    atomicAdd(&h[l3], 1);
    __syncthreads();

    const int myCnt = h[tid];
    if (tid < NLd) blockCnt[(size_t)g * NLd + tid] = myCnt;
    // in-place inclusive Hillis-Steele scan of h
    for (int off = 1; off < 1024; off <<= 1) {
        int t = (tid >= off) ? h[tid - off] : 0;
        __syncthreads();
        h[tid] += t;
        __syncthreads();
    }
    const int myst = h[tid] - myCnt;       // my label's run start
    __syncthreads();
    h[tid] = myst;                         // cursor init
    __syncthreads();

    // block-local ranks of my 4 pixels (registers)
    const int r0 = atomicAdd(&h[l0], 1) & (PXW - 1);
    const int r1 = atomicAdd(&h[l1], 1) & (PXW - 1);
    const int r2 = atomicAdd(&h[l2], 1) & (PXW - 1);
    const int r3 = atomicAdd(&h[l3], 1) & (PXW - 1);

    const float* __restrict__ xb = x + (((size_t)b * Cd) << 18) + p0 + 4 * tid;
    float* __restrict__ pout = partial + (size_t)g * NSL * PROW;

    // prologue: load + pack slice 0 (4 channels)
    floatx4 v0, v1, v2, v3;
    v0 = __builtin_nontemporal_load((const floatx4*)(xb + ((size_t)0 << 18)));
    v1 = __builtin_nontemporal_load((const floatx4*)(xb + ((size_t)1 << 18)));
    v2 = __builtin_nontemporal_load((const floatx4*)(xb + ((size_t)2 << 18)));
    v3 = __builtin_nontemporal_load((const floatx4*)(xb + ((size_t)3 << 18)));
    uint2 pk0, pk1, pk2, pk3;
    pk0.x = pack2(v0[0], v1[0]); pk0.y = pack2(v2[0], v3[0]);
    pk1.x = pack2(v0[1], v1[1]); pk1.y = pack2(v2[1], v3[1]);
    pk2.x = pack2(v0[2], v1[2]); pk2.y = pack2(v2[2], v3[2]);
    pk3.x = pack2(v0[3], v1[3]); pk3.y = pack2(v2[3], v3[3]);

    for (int s = 0; s < NSL; ++s) {
        __syncthreads();                 // previous slice's sums complete
        ordered[r0] = pk0;
        ordered[r1] = pk1;
        ordered[r2] = pk2;
        ordered[r3] = pk3;
        // issue next slice's loads NOW: latency hides under the sum phase
        if (s + 1 < NSL) {
            const float* nb = xb + (((size_t)((s + 1) * CSL)) << 18);
            v0 = __builtin_nontemporal_load((const floatx4*)(nb + ((size_t)0 << 18)));
            v1 = __builtin_nontemporal_load((const floatx4*)(nb + ((size_t)1 << 18)));
            v2 = __builtin_nontemporal_load((const floatx4*)(nb + ((size_t)2 << 18)));
            v3 = __builtin_nontemporal_load((const floatx4*)(nb + ((size_t)3 << 18)));
        }
        __syncthreads();                 // scatter visible

        if (tid < NLd) {
            float a0 = 0, a1 = 0, a2 = 0, a3 = 0;
            for (int i = 0; i < myCnt; ++i) {
                uint2 u = ordered[(myst + i) & (PXW - 1)];
                a0 += bflo(u.x); a1 += bfhi(u.x);
                a2 += bflo(u.y); a3 += bfhi(u.y);
            }
            float4 o; o.x = a0; o.y = a1; o.z = a2; o.w = a3;
            *(float4*)(pout + (size_t)s * PROW + tid * 4) = o;
        }
        if (s + 1 < NSL) {               // pack after sums (waits on loads)
            pk0.x = pack2(v0[0], v1[0]); pk0.y = pack2(v2[0], v3[0]);
            pk1.x = pack2(v0[1], v1[1]); pk1.y = pack2(v2[1], v3[1]);
            pk2.x = pack2(v0[2], v1[2]); pk2.y = pack2(v2[2], v3[2]);
            pk3.x = pack2(v0[3], v1[3]); pk3.y = pack2(v2[3], v3[3]);
        }
    }
}

// ---------------------------------------------------------------------------
// 2) combine: reduce 64 windows -> means[b][l][c] (fused divide).
//    grid = (63, B) x 256 thr; tid -> (s = tid>>4, ll = tid&15).
//    16 consecutive threads read 256B contiguous per (window, s).
// ---------------------------------------------------------------------------
__global__ __launch_bounds__(256)
void combine_kernel(const float* __restrict__ partial,
                    const int* __restrict__ blockCnt,
                    float* __restrict__ means) {
    __shared__ float ninv[16];
    const int tid = threadIdx.x;
    const int b   = blockIdx.y;
    const int l0  = blockIdx.x * 16;
    const int s   = tid >> 4;       // slice 0..15
    const int ll  = tid & 15;       // label within group
    const int l   = l0 + ll;

    if (tid < 16) {
        const int li = (l0 + tid < NLd) ? (l0 + tid) : (NLd - 1);
        int n = 0;
        for (int g = 0; g < WIN; ++g)
            n += blockCnt[(size_t)(b * WIN + g) * NLd + li];
        ninv[tid] = 1.0f / (float)(n > 0 ? n : 1);
    }
    __syncthreads();

    if (l < NLd) {
        float4 r; r.x = 0; r.y = 0; r.z = 0; r.w = 0;
        const float* __restrict__ pb =
            partial + (size_t)b * WIN * NSL * PROW + (size_t)s * PROW + l * 4;
        for (int g = 0; g < WIN; ++g) {
            float4 p = *(const float4*)(pb + (size_t)g * NSL * PROW);
            r.x += p.x; r.y += p.y; r.z += p.z; r.w += p.w;
        }
        const float sc = ninv[ll];
        float4 o; o.x = r.x * sc; o.y = r.y * sc; o.z = r.z * sc; o.w = r.w * sc;
        *(float4*)(means + (((size_t)(b * NLd + l)) << 6) + s * 4) = o;
    }
}

// ---------------------------------------------------------------------------
// 3) gather means at edge endpoints + copy edge weights.
// ---------------------------------------------------------------------------
__global__ __launch_bounds__(256)
void gather_kernel(const float* __restrict__ means,
                   const int* __restrict__ edges,
                   const float* __restrict__ ew,
                   float* __restrict__ out) {
    const int t  = blockIdx.x * 256 + threadIdx.x;   // 0 .. B*NS*C-1
    const int bs = t >> 6;                           // b*NS + s
    const int c  = t & 63;
    const int b  = bs >> 11;                         // NS = 2048

    const int la = clampl(edges[bs * 2 + 0]);
    const int lb = clampl(edges[bs * 2 + 1]);

    out[t] = means[((size_t)(b * NLd + la) << 6) + c];
    out[(size_t)Bd * NSd * Cd + t] = means[((size_t)(b * NLd + lb) << 6) + c];
    if (t < Bd * NSd)
        out[2 * (size_t)Bd * NSd * Cd + t] = ew[t];
}

// ===========================================================================
// FALLBACK PATH (R1 design, known-good 371 us; needs ~1 MB ws)
// ===========================================================================
#define WS_FB_ELEMS (Bd * Cd * NLd + Bd * NLd)

__global__ __launch_bounds__(256)
void fb_sums_kernel(const float* __restrict__ x, const int* __restrict__ lab,
                    float* __restrict__ sums) {
    __shared__ float lsum[NLd];
    const int tid   = threadIdx.x;
    const int chunk = blockIdx.x;
    const int c     = blockIdx.y;
    const int b     = blockIdx.z;

    for (int l = tid; l < NLd; l += 256) lsum[l] = 0.0f;
    __syncthreads();

    const float4* __restrict__ xp =
        (const float4*)x + (size_t)(b * Cd + c) * (HWp / 4);
    const int4* __restrict__ lp = (const int4*)lab + (size_t)b * (HWp / 4);

    const int nvec = HWp / 16;
    const int v0 = chunk * nvec, v1 = v0 + nvec;
    for (int v = v0 + tid; v < v1; v += 256) {
        float4 xv = xp[v];
        int4   lv = lp[v];
        atomicAdd(&lsum[clampl(lv.x)], xv.x);
        atomicAdd(&lsum[clampl(lv.y)], xv.y);
        atomicAdd(&lsum[clampl(lv.z)], xv.z);
        atomicAdd(&lsum[clampl(lv.w)], xv.w);
    }
    __syncthreads();

    float* __restrict__ dst = sums + (size_t)(b * Cd + c) * NLd;
    for (int l = tid; l < NLd; l += 256)
        atomicAdd(&dst[l], lsum[l]);
}

__global__ __launch_bounds__(256)
void fb_counts_kernel(const int* __restrict__ lab, float* __restrict__ counts) {
    __shared__ unsigned lcnt[NLd];
    const int tid   = threadIdx.x;
    const int chunk = blockIdx.x;
    const int b     = blockIdx.y;

    for (int l = tid; l < NLd; l += 256) lcnt[l] = 0u;
    __syncthreads();

    const int4* __restrict__ lp = (const int4*)lab + (size_t)b * (HWp / 4);
    const int nvec = HWp / 16;
    const int v0 = chunk * nvec, v1 = v0 + nvec;
    for (int v = v0 + tid; v < v1; v += 256) {
        int4 lv = lp[v];
        atomicAdd(&lcnt[clampl(lv.x)], 1u);
        atomicAdd(&lcnt[clampl(lv.y)], 1u);
        atomicAdd(&lcnt[clampl(lv.z)], 1u);
        atomicAdd(&lcnt[clampl(lv.w)], 1u);
    }
    __syncthreads();

    float* __restrict__ dst = counts + (size_t)b * NLd;
    for (int l = tid; l < NLd; l += 256)
        atomicAdd(&dst[l], (float)lcnt[l]);
}

__global__ __launch_bounds__(256)
void fb_gather_kernel(const float* __restrict__ sums,
                      const float* __restrict__ counts,
                      const int* __restrict__ edges,
                      const float* __restrict__ ew,
                      float* __restrict__ out) {
    const int t  = blockIdx.x * 256 + threadIdx.x;
    const int bs = t >> 6;
    const int c  = t & 63;
    const int b  = bs >> 11;

    const int la = clampl(edges[bs * 2 + 0]);
    const int lb = clampl(edges[bs * 2 + 1]);

    const float ca = fmaxf(counts[b * NLd + la], 1.0f);
    const float cb = fmaxf(counts[b * NLd + lb], 1.0f);

    const size_t plane = (size_t)(b * Cd + c) * NLd;
    out[t] = sums[plane + la] / ca;
    out[(size_t)Bd * NSd * Cd + t] = sums[plane + lb] / cb;
    if (t < Bd * NSd)
        out[2 * (size_t)Bd * NSd * Cd + t] = ew[t];
}

extern "C" void kernel_launch(void* const* d_in, const int* in_sizes, int n_in,
                              void* d_out, int out_size, void* d_ws, size_t ws_size,
                              hipStream_t stream) {
    const float* x     = (const float*)d_in[0];   // [B,C,H,W] f32
    const int*   lab   = (const int*)d_in[1];     // [B,1,H,W] i32
    const int*   edges = (const int*)d_in[2];     // [B,NS,2] i32
    const float* ew    = (const float*)d_in[3];   // [B,NS] f32
    float*       out   = (float*)d_out;

    const int n_gather = Bd * NSd * Cd;   // 524288

    if (ws_size >= (size_t)WS_ELEMS * sizeof(float)) {
        float* partial  = (float*)d_ws + OFF_PART;
        int*   blockCnt = (int*)d_ws + OFF_BCNT;
        float* means    = (float*)d_ws + OFF_MEANS;

        // no memset needed: partial/blockCnt/means are fully overwritten
        fused_kernel<<<NBLK, 1024, 0, stream>>>(x, lab, blockCnt, partial);
        combine_kernel<<<dim3(63, Bd), 256, 0, stream>>>(partial, blockCnt, means);
        gather_kernel<<<n_gather / 256, 256, 0, stream>>>(means, edges, ew, out);
    } else {
        // ---- fallback: R1 atomic path ----
        float* sums   = (float*)d_ws;
        float* counts = sums + (size_t)Bd * Cd * NLd;

        hipMemsetAsync(d_ws, 0, (size_t)WS_FB_ELEMS * sizeof(float), stream);

        fb_sums_kernel<<<dim3(4, Cd, Bd), 256, 0, stream>>>(x, lab, sums);
        fb_counts_kernel<<<dim3(4, Bd), 256, 0, stream>>>(lab, counts);
        fb_gather_kernel<<<n_gather / 256, 256, 0, stream>>>(sums, counts, edges, ew, out);
    }
}

// Round 13
// 78.525 us; speedup vs baseline: 1.7459x; 1.1019x over previous
//
#include <hip/hip_runtime.h>

// Problem constants (fixed by the reference setup)
#define Bd 4
#define Cd 64
#define HWp 262144           // 512*512 = 2^18 pixels per image
#define NSd 2048
#define NLd 1000

#define NWIN   256           // windows total (64 per image)
#define PXW    4096          // pixels per window
#define NSL    16            // channel slices (4 ch each)
#define CSL    4             // channels per slice
#define SPB    8             // slices per block (2 blocks per window)
#define PU32   2000          // u32 per partial slice-row (1000 labels x uint2)

typedef float __attribute__((ext_vector_type(4))) floatx4;

// ===========================================================================
// FAST PATH (fused, 2 blocks/CU for cross-block latency hiding):
//   fused  : grid (2, 256). Each block: {hist -> scan -> ranks} for its
//            window, then 8 slices {scatter bf16x4 rows to LDS -> per-label
//            lane sums -> bf16 partial store}. Two co-resident blocks
//            interleave load-stall with sum/scatter phases.
//   combine: reduce 64 windows -> means (f32 accum, fused divide)
//   gather : edge endpoint means + edge weights
// ws layout (4B units):
//   partial  [NWIN*NSL*PU32] u32    bf16-pair label sums
//   blockCnt [NWIN*NL]       int
//   means    [B*NL*C]        float
// ===========================================================================
#define OFF_PART  0
#define OFF_BCNT  (NWIN * NSL * PU32)
#define OFF_MEANS (OFF_BCNT + NWIN * NLd)
#define WS_ELEMS  (OFF_MEANS + Bd * NLd * Cd)

__device__ __forceinline__ unsigned short f2bf(float f) {
    unsigned u = __float_as_uint(f);
    u += 0x7FFFu + ((u >> 16) & 1u);          // round-to-nearest-even
    return (unsigned short)(u >> 16);
}
__device__ __forceinline__ unsigned pack2(float lo, float hi) {
    return ((unsigned)f2bf(hi) << 16) | (unsigned)f2bf(lo);
}
__device__ __forceinline__ float bflo(unsigned u) { return __uint_as_float(u << 16); }
__device__ __forceinline__ float bfhi(unsigned u) { return __uint_as_float(u & 0xFFFF0000u); }
__device__ __forceinline__ int clampl(int l) {
    return (l < 0) ? 0 : (l >= NLd ? NLd - 1 : l);
}

// ---------------------------------------------------------------------------
// 1) fused kernel. grid = (2, NWIN), block = 1024 (thread owns 4 px).
//    LDS 36KB, VGPR forced <=64 -> 2 blocks/CU co-resident.
// ---------------------------------------------------------------------------
__global__ __launch_bounds__(1024, 8)
void fused_kernel(const float* __restrict__ x, const int* __restrict__ lab,
                  int* __restrict__ blockCnt, unsigned* __restrict__ partial) {
    __shared__ int h[1024];          // hist -> scan -> cursor (reused)
    __shared__ uint2 ordered[PXW];   // 32 KB: rank-ordered bf16x4 pixel rows

    const int tid  = threadIdx.x;
    const int half = blockIdx.x;     // 0..1 (slice group)
    const int w    = blockIdx.y;     // 0..255 (window)
    const int b    = w >> 6;
    const int p0   = (w & 63) * PXW;

    h[tid] = 0;
    __syncthreads();

    const int4 lv = ((const int4*)(lab + ((size_t)b << 18) + p0))[tid];
    const int l0 = clampl(lv.x), l1 = clampl(lv.y),
              l2 = clampl(lv.z), l3 = clampl(lv.w);
    atomicAdd(&h[l0], 1);
    atomicAdd(&h[l1], 1);
    atomicAdd(&h[l2], 1);
    atomicAdd(&h[l3], 1);
    __syncthreads();

    const int myCnt = h[tid];
    if (half == 0 && tid < NLd) blockCnt[(size_t)w * NLd + tid] = myCnt;
    // in-place inclusive Hillis-Steele scan of h
    for (int off = 1; off < 1024; off <<= 1) {
        int t = (tid >= off) ? h[tid - off] : 0;
        __syncthreads();
        h[tid] += t;
        __syncthreads();
    }
    const int myst = h[tid] - myCnt;       // my label's run start
    __syncthreads();
    h[tid] = myst;                         // cursor init
    __syncthreads();

    const int r0 = atomicAdd(&h[l0], 1) & (PXW - 1);
    const int r1 = atomicAdd(&h[l1], 1) & (PXW - 1);
    const int r2 = atomicAdd(&h[l2], 1) & (PXW - 1);
    const int r3 = atomicAdd(&h[l3], 1) & (PXW - 1);

    // my slice group's channel base
    const float* __restrict__ xs =
        x + (((size_t)b * Cd + half * (SPB * CSL)) << 18) + p0 + 4 * tid;
    unsigned* __restrict__ pout =
        partial + ((size_t)w * NSL + half * SPB) * PU32;

    // prologue: load + pack local slice 0
    floatx4 v0, v1, v2, v3;
    v0 = __builtin_nontemporal_load((const floatx4*)(xs + ((size_t)0 << 18)));
    v1 = __builtin_nontemporal_load((const floatx4*)(xs + ((size_t)1 << 18)));
    v2 = __builtin_nontemporal_load((const floatx4*)(xs + ((size_t)2 << 18)));
    v3 = __builtin_nontemporal_load((const floatx4*)(xs + ((size_t)3 << 18)));
    uint2 pk0, pk1, pk2, pk3;
    pk0.x = pack2(v0[0], v1[0]); pk0.y = pack2(v2[0], v3[0]);
    pk1.x = pack2(v0[1], v1[1]); pk1.y = pack2(v2[1], v3[1]);
    pk2.x = pack2(v0[2], v1[2]); pk2.y = pack2(v2[2], v3[2]);
    pk3.x = pack2(v0[3], v1[3]); pk3.y = pack2(v2[3], v3[3]);

    for (int s = 0; s < SPB; ++s) {
        __syncthreads();                 // previous slice's sums complete
        ordered[r0] = pk0;
        ordered[r1] = pk1;
        ordered[r2] = pk2;
        ordered[r3] = pk3;
        if (s + 1 < SPB) {               // issue next slice's loads now
            const float* nb = xs + (((size_t)((s + 1) * CSL)) << 18);
            v0 = __builtin_nontemporal_load((const floatx4*)(nb + ((size_t)0 << 18)));
            v1 = __builtin_nontemporal_load((const floatx4*)(nb + ((size_t)1 << 18)));
            v2 = __builtin_nontemporal_load((const floatx4*)(nb + ((size_t)2 << 18)));
            v3 = __builtin_nontemporal_load((const floatx4*)(nb + ((size_t)3 << 18)));
        }
        __syncthreads();                 // scatter visible

        if (tid < NLd) {
            float a0 = 0, a1 = 0, a2 = 0, a3 = 0;
            for (int i = 0; i < myCnt; ++i) {
                uint2 u = ordered[(myst + i) & (PXW - 1)];
                a0 += bflo(u.x); a1 += bfhi(u.x);
                a2 += bflo(u.y); a3 += bfhi(u.y);
            }
            uint2 o; o.x = pack2(a0, a1); o.y = pack2(a2, a3);
            *(uint2*)(pout + (size_t)s * PU32 + tid * 2) = o;
        }
        if (s + 1 < SPB) {               // pack after sums (waits on loads)
            pk0.x = pack2(v0[0], v1[0]); pk0.y = pack2(v2[0], v3[0]);
            pk1.x = pack2(v0[1], v1[1]); pk1.y = pack2(v2[1], v3[1]);
            pk2.x = pack2(v0[2], v1[2]); pk2.y = pack2(v2[2], v3[2]);
            pk3.x = pack2(v0[3], v1[3]); pk3.y = pack2(v2[3], v3[3]);
        }
    }
}

// ---------------------------------------------------------------------------
// 2) combine: reduce 64 windows -> means[b][l][c], f32 accumulate.
//    grid = (63, B) x 256 thr; tid -> (s = tid>>4, ll = tid&15).
// ---------------------------------------------------------------------------
__global__ __launch_bounds__(256)
void combine_kernel(const unsigned* __restrict__ partial,
                    const int* __restrict__ blockCnt,
                    float* __restrict__ means) {
    __shared__ float ninv[16];
    const int tid = threadIdx.x;
    const int b   = blockIdx.y;
    const int l0  = blockIdx.x * 16;
    const int s   = tid >> 4;       // slice 0..15
    const int ll  = tid & 15;       // label within group
    const int l   = l0 + ll;

    if (tid < 16) {
        const int li = (l0 + tid < NLd) ? (l0 + tid) : (NLd - 1);
        int n = 0;
        for (int g = 0; g < 64; ++g)
            n += blockCnt[(size_t)(b * 64 + g) * NLd + li];
        ninv[tid] = 1.0f / (float)(n > 0 ? n : 1);
    }
    __syncthreads();

    if (l < NLd) {
        float r0 = 0, r1 = 0, r2 = 0, r3 = 0;
        const unsigned* __restrict__ pb =
            partial + ((size_t)(b * 64) * NSL + s) * PU32 + l * 2;
        for (int g = 0; g < 64; ++g) {
            uint2 p = *(const uint2*)(pb + (size_t)g * NSL * PU32);
            r0 += bflo(p.x); r1 += bfhi(p.x);
            r2 += bflo(p.y); r3 += bfhi(p.y);
        }
        const float sc = ninv[ll];
        float4 o; o.x = r0 * sc; o.y = r1 * sc; o.z = r2 * sc; o.w = r3 * sc;
        *(float4*)(means + (((size_t)(b * NLd + l)) << 6) + s * 4) = o;
    }
}

// ---------------------------------------------------------------------------
// 3) gather means at edge endpoints + copy edge weights.
// ---------------------------------------------------------------------------
__global__ __launch_bounds__(256)
void gather_kernel(const float* __restrict__ means,
                   const int* __restrict__ edges,
                   const float* __restrict__ ew,
                   float* __restrict__ out) {
    const int t  = blockIdx.x * 256 + threadIdx.x;   // 0 .. B*NS*C-1
    const int bs = t >> 6;                           // b*NS + s
    const int c  = t & 63;
    const int b  = bs >> 11;                         // NS = 2048

    const int la = clampl(edges[bs * 2 + 0]);
    const int lb = clampl(edges[bs * 2 + 1]);

    out[t] = means[((size_t)(b * NLd + la) << 6) + c];
    out[(size_t)Bd * NSd * Cd + t] = means[((size_t)(b * NLd + lb) << 6) + c];
    if (t < Bd * NSd)
        out[2 * (size_t)Bd * NSd * Cd + t] = ew[t];
}

// ===========================================================================
// FALLBACK PATH (R1 design, known-good 371 us; needs ~1 MB ws)
// ===========================================================================
#define WS_FB_ELEMS (Bd * Cd * NLd + Bd * NLd)

__global__ __launch_bounds__(256)
void fb_sums_kernel(const float* __restrict__ x, const int* __restrict__ lab,
                    float* __restrict__ sums) {
    __shared__ float lsum[NLd];
    const int tid   = threadIdx.x;
    const int chunk = blockIdx.x;
    const int c     = blockIdx.y;
    const int b     = blockIdx.z;

    for (int l = tid; l < NLd; l += 256) lsum[l] = 0.0f;
    __syncthreads();

    const float4* __restrict__ xp =
        (const float4*)x + (size_t)(b * Cd + c) * (HWp / 4);
    const int4* __restrict__ lp = (const int4*)lab + (size_t)b * (HWp / 4);

    const int nvec = HWp / 16;
    const int v0 = chunk * nvec, v1 = v0 + nvec;
    for (int v = v0 + tid; v < v1; v += 256) {
        float4 xv = xp[v];
        int4   lv = lp[v];
        atomicAdd(&lsum[clampl(lv.x)], xv.x);
        atomicAdd(&lsum[clampl(lv.y)], xv.y);
        atomicAdd(&lsum[clampl(lv.z)], xv.z);
        atomicAdd(&lsum[clampl(lv.w)], xv.w);
    }
    __syncthreads();

    float* __restrict__ dst = sums + (size_t)(b * Cd + c) * NLd;
    for (int l = tid; l < NLd; l += 256)
        atomicAdd(&dst[l], lsum[l]);
}

__global__ __launch_bounds__(256)
void fb_counts_kernel(const int* __restrict__ lab, float* __restrict__ counts) {
    __shared__ unsigned lcnt[NLd];
    const int tid   = threadIdx.x;
    const int chunk = blockIdx.x;
    const int b     = blockIdx.y;

    for (int l = tid; l < NLd; l += 256) lcnt[l] = 0u;
    __syncthreads();

    const int4* __restrict__ lp = (const int4*)lab + (size_t)b * (HWp / 4);
    const int nvec = HWp / 16;
    const int v0 = chunk * nvec, v1 = v0 + nvec;
    for (int v = v0 + tid; v < v1; v += 256) {
        int4 lv = lp[v];
        atomicAdd(&lcnt[clampl(lv.x)], 1u);
        atomicAdd(&lcnt[clampl(lv.y)], 1u);
        atomicAdd(&lcnt[clampl(lv.z)], 1u);
        atomicAdd(&lcnt[clampl(lv.w)], 1u);
    }
    __syncthreads();

    float* __restrict__ dst = counts + (size_t)b * NLd;
    for (int l = tid; l < NLd; l += 256)
        atomicAdd(&dst[l], (float)lcnt[l]);
}

__global__ __launch_bounds__(256)
void fb_gather_kernel(const float* __restrict__ sums,
                      const float* __restrict__ counts,
                      const int* __restrict__ edges,
                      const float* __restrict__ ew,
                      float* __restrict__ out) {
    const int t  = blockIdx.x * 256 + threadIdx.x;
    const int bs = t >> 6;
    const int c  = t & 63;
    const int b  = bs >> 11;

    const int la = clampl(edges[bs * 2 + 0]);
    const int lb = clampl(edges[bs * 2 + 1]);

    const float ca = fmaxf(counts[b * NLd + la], 1.0f);
    const float cb = fmaxf(counts[b * NLd + lb], 1.0f);

    const size_t plane = (size_t)(b * Cd + c) * NLd;
    out[t] = sums[plane + la] / ca;
    out[(size_t)Bd * NSd * Cd + t] = sums[plane + lb] / cb;
    if (t < Bd * NSd)
        out[2 * (size_t)Bd * NSd * Cd + t] = ew[t];
}

extern "C" void kernel_launch(void* const* d_in, const int* in_sizes, int n_in,
                              void* d_out, int out_size, void* d_ws, size_t ws_size,
                              hipStream_t stream) {
    const float* x     = (const float*)d_in[0];   // [B,C,H,W] f32
    const int*   lab   = (const int*)d_in[1];     // [B,1,H,W] i32
    const int*   edges = (const int*)d_in[2];     // [B,NS,2] i32
    const float* ew    = (const float*)d_in[3];   // [B,NS] f32
    float*       out   = (float*)d_out;

    const int n_gather = Bd * NSd * Cd;   // 524288

    if (ws_size >= (size_t)WS_ELEMS * sizeof(float)) {
        unsigned* partial  = (unsigned*)d_ws + OFF_PART;
        int*      blockCnt = (int*)d_ws + OFF_BCNT;
        float*    means    = (float*)d_ws + OFF_MEANS;

        // no memset needed: partial/blockCnt/means are fully overwritten
        fused_kernel<<<dim3(2, NWIN), 1024, 0, stream>>>(x, lab, blockCnt, partial);
        combine_kernel<<<dim3(63, Bd), 256, 0, stream>>>(partial, blockCnt, means);
        gather_kernel<<<n_gather / 256, 256, 0, stream>>>(means, edges, ew, out);
    } else {
        // ---- fallback: R1 atomic path ----
        float* sums   = (float*)d_ws;
        float* counts = sums + (size_t)Bd * Cd * NLd;

        hipMemsetAsync(d_ws, 0, (size_t)WS_FB_ELEMS * sizeof(float), stream);

        fb_sums_kernel<<<dim3(4, Cd, Bd), 256, 0, stream>>>(x, lab, sums);
        fb_counts_kernel<<<dim3(4, Bd), 256, 0, stream>>>(lab, counts);
        fb_gather_kernel<<<n_gather / 256, 256, 0, stream>>>(sums, counts, edges, ew, out);
    }
}